// Round 1
// baseline (842.165 us; speedup 1.0000x reference)
//
#include <hip/hip_runtime.h>

// CompressibleFluidLoss: gather-compute-scatter finite difference on a graph.
// out[i] = mean_{e: src=i, ea.x!=0}((vp_x[dst]-vp_x[src])/ea.x)
//        + mean_{e: src=i, ea.y!=0}((vp_y[dst]-vp_y[src])/ea.y)
//        + (p[i]-p_prev[i])/dt
// where vp = v * p (per-node).

__global__ void zero_f4(float4* ws, int n4) {
    int i = blockIdx.x * blockDim.x + threadIdx.x;
    int stride = gridDim.x * blockDim.x;
    for (; i < n4; i += stride) ws[i] = make_float4(0.f, 0.f, 0.f, 0.f);
}

__global__ void edge_scatter(const float2* __restrict__ v,
                             const float* __restrict__ p,
                             const float2* __restrict__ ea,
                             const int* __restrict__ src_idx,
                             const int* __restrict__ dst_idx,
                             float* __restrict__ sum_x,
                             float* __restrict__ cnt_x,
                             float* __restrict__ sum_y,
                             float* __restrict__ cnt_y,
                             int E) {
    int e = blockIdx.x * blockDim.x + threadIdx.x;
    if (e >= E) return;
    int s = src_idx[e];
    int d = dst_idx[e];
    float2 a = ea[e];
    // gathers: node arrays (12 MB total) are L2/L3 resident
    float ps = p[s], pd = p[d];
    float2 vs = v[s], vd = v[d];
    if (a.x != 0.f) {
        float c = (vd.x * pd - vs.x * ps) / a.x;
        atomicAdd(&sum_x[s], c);
        atomicAdd(&cnt_x[s], 1.f);
    }
    if (a.y != 0.f) {
        float c = (vd.y * pd - vs.y * ps) / a.y;
        atomicAdd(&sum_y[s], c);
        atomicAdd(&cnt_y[s], 1.f);
    }
}

__global__ void node_final(const float* __restrict__ sum_x,
                           const float* __restrict__ cnt_x,
                           const float* __restrict__ sum_y,
                           const float* __restrict__ cnt_y,
                           const float* __restrict__ p,
                           const float* __restrict__ p_prev,
                           const float* __restrict__ dt_ptr,
                           float* __restrict__ out,
                           int N) {
    int i = blockIdx.x * blockDim.x + threadIdx.x;
    int stride = gridDim.x * blockDim.x;
    float inv_dt = 1.0f / dt_ptr[0];
    for (; i < N; i += stride) {
        float dx = sum_x[i] / fmaxf(cnt_x[i], 1.f);
        float dy = sum_y[i] / fmaxf(cnt_y[i], 1.f);
        out[i] = dx + dy + (p[i] - p_prev[i]) * inv_dt;
    }
}

extern "C" void kernel_launch(void* const* d_in, const int* in_sizes, int n_in,
                              void* d_out, int out_size, void* d_ws, size_t ws_size,
                              hipStream_t stream) {
    const float2* v_x   = (const float2*)d_in[0];
    const float*  p_x   = (const float*)d_in[2];
    const float*  p_prev= (const float*)d_in[3];
    const float*  dt    = (const float*)d_in[9];
    const float2* ea    = (const float2*)d_in[10];
    const int*    eidx  = (const int*)d_in[11];

    const int N = in_sizes[2];        // nodes (p_x has N elements)
    const int E = in_sizes[10] / 2;   // edges (edge_attr has 2E elements)

    const int* src_idx = eidx;        // edge_index[0, :]
    const int* dst_idx = eidx + E;    // edge_index[1, :]

    float* ws    = (float*)d_ws;
    float* sum_x = ws + 0 * (size_t)N;
    float* cnt_x = ws + 1 * (size_t)N;
    float* sum_y = ws + 2 * (size_t)N;
    float* cnt_y = ws + 3 * (size_t)N;

    // zero the 4 N-float accumulators (16 MiB) every call — ws is poisoned
    int n4 = (4 * N) / 4;  // float4 count
    zero_f4<<<2048, 256, 0, stream>>>((float4*)ws, n4);

    edge_scatter<<<(E + 255) / 256, 256, 0, stream>>>(
        v_x, p_x, ea, src_idx, dst_idx, sum_x, cnt_x, sum_y, cnt_y, E);

    node_final<<<2048, 256, 0, stream>>>(
        sum_x, cnt_x, sum_y, cnt_y, p_x, p_prev, dt, (float*)d_out, N);
}

// Round 2
// 841.346 us; speedup vs baseline: 1.0010x; 1.0010x over previous
//
#include <hip/hip_runtime.h>

// CompressibleFluidLoss: gather-compute-scatter finite difference on a graph.
// out[i] = mean_{e: src=i, ea.x!=0}((vp_x[dst]-vp_x[src])/ea.x)
//        + mean_{e: src=i, ea.y!=0}((vp_y[dst]-vp_y[src])/ea.y)
//        + (p[i]-p_prev[i])/dt ,  vp = v * p per node.
//
// Round 2: reduce random line transactions per edge 6 -> ~3:
//   - pre-pass computes vp (float2) so each endpoint gather is ONE line
//   - accumulators interleaved as float4 {sum_x, cnt_x, sum_y, cnt_y} so all
//     atomics of an edge hit one 16B segment
//   - early-out for edges with both masks zero (skips gathers, ~25%)

__global__ void node_pre(const float2* __restrict__ v,
                         const float* __restrict__ p,
                         float2* __restrict__ vp,
                         float4* __restrict__ acc,
                         int N) {
    int i = blockIdx.x * blockDim.x + threadIdx.x;
    int stride = gridDim.x * blockDim.x;
    for (; i < N; i += stride) {
        float2 vi = v[i];
        float pi = p[i];
        vp[i] = make_float2(vi.x * pi, vi.y * pi);
        acc[i] = make_float4(0.f, 0.f, 0.f, 0.f);
    }
}

__global__ void edge_scatter(const float2* __restrict__ vp,
                             const float2* __restrict__ ea,
                             const int* __restrict__ src_idx,
                             const int* __restrict__ dst_idx,
                             float4* __restrict__ acc,
                             int E) {
    int e = blockIdx.x * blockDim.x + threadIdx.x;
    if (e >= E) return;
    float2 a = ea[e];
    bool mx = (a.x != 0.f);
    bool my = (a.y != 0.f);
    if (!mx && !my) return;
    int s = src_idx[e];
    int d = dst_idx[e];
    float2 vs = vp[s];      // one random line
    float2 vd = vp[d];      // one random line
    float* accs = (float*)&acc[s];  // one random line for all atomics
    if (mx) {
        atomicAdd(accs + 0, (vd.x - vs.x) / a.x);
        atomicAdd(accs + 1, 1.f);
    }
    if (my) {
        atomicAdd(accs + 2, (vd.y - vs.y) / a.y);
        atomicAdd(accs + 3, 1.f);
    }
}

__global__ void node_final(const float4* __restrict__ acc,
                           const float* __restrict__ p,
                           const float* __restrict__ p_prev,
                           const float* __restrict__ dt_ptr,
                           float* __restrict__ out,
                           int N) {
    int i = blockIdx.x * blockDim.x + threadIdx.x;
    int stride = gridDim.x * blockDim.x;
    float inv_dt = 1.0f / dt_ptr[0];
    for (; i < N; i += stride) {
        float4 A = acc[i];
        float dx = A.x / fmaxf(A.y, 1.f);
        float dy = A.z / fmaxf(A.w, 1.f);
        out[i] = dx + dy + (p[i] - p_prev[i]) * inv_dt;
    }
}

extern "C" void kernel_launch(void* const* d_in, const int* in_sizes, int n_in,
                              void* d_out, int out_size, void* d_ws, size_t ws_size,
                              hipStream_t stream) {
    const float2* v_x    = (const float2*)d_in[0];
    const float*  p_x    = (const float*)d_in[2];
    const float*  p_prev = (const float*)d_in[3];
    const float*  dt     = (const float*)d_in[9];
    const float2* ea     = (const float2*)d_in[10];
    const int*    eidx   = (const int*)d_in[11];

    const int N = in_sizes[2];        // nodes (p_x has N elements)
    const int E = in_sizes[10] / 2;   // edges (edge_attr has 2E elements)

    const int* src_idx = eidx;        // edge_index[0, :]
    const int* dst_idx = eidx + E;    // edge_index[1, :]

    // ws layout: vp (float2 x N = 8MB) | acc (float4 x N = 16MB)
    float2* vp  = (float2*)d_ws;
    float4* acc = (float4*)((char*)d_ws + (size_t)N * sizeof(float2));

    node_pre<<<2048, 256, 0, stream>>>(v_x, p_x, vp, acc, N);

    edge_scatter<<<(E + 255) / 256, 256, 0, stream>>>(
        vp, ea, src_idx, dst_idx, acc, E);

    node_final<<<2048, 256, 0, stream>>>(
        acc, p_x, p_prev, dt, (float*)d_out, N);
}